// Round 7
// baseline (299.355 us; speedup 1.0000x reference)
//
#include <hip/hip_runtime.h>

// SoftDecisionTree: BATCH=1M, DIM=64, DEPTH=7 -> 127 nodes, 128 leaves.
// Round 7 = round 6 structure (MFMA logits, f16 P in per-wave LDS, walk with
// line-complete NT stores, zero barriers, pipelined x loads) with an occupancy
// push:
//   - bfrag (64 VGPRs) no longer hoisted: W fragments reloaded per chunk from
//     global (w = 32KB fp32, L1-resident; anti-hoist asm barrier keeps the
//     compiler from re-hoisting). leafv likewise reloaded per chunk.
//   - __launch_bounds__(256, 4): 4 blocks/CU (16 waves/CU) instead of 3.
// Rationale: stores only issue during walk phases; 12 waves/CU left the HBM
// write stream bursty (~60% effective BW). +33% resident waves smooths it.

typedef float v4f __attribute__((ext_vector_type(4)));
typedef _Float16 h8 __attribute__((ext_vector_type(8)));
typedef unsigned int u32;
typedef u32 u32x2 __attribute__((ext_vector_type(2)));

constexpr int BATCH = 1 << 20;
constexpr int PSTRIDE = 40;           // bytes per node: 16 rows * 2B + 8 pad
constexpr int PWAVE = 128 * PSTRIDE;  // 5120 B per wave

__device__ __forceinline__ float fast_sigmoid(float z) {
    float e = __builtin_amdgcn_exp2f(z * -1.44269504088896340736f);
    return __builtin_amdgcn_rcpf(1.0f + e);
}

__device__ __forceinline__ u32 pk2(float a, float b) {
    return __builtin_bit_cast(u32, __builtin_amdgcn_cvt_pkrtz(a, b));
}

__device__ __forceinline__ h8 cvt8(v4f lo, v4f hi) {
    union { u32 w[4]; h8 v; } u;
    u.w[0] = pk2(lo.x, lo.y);
    u.w[1] = pk2(lo.z, lo.w);
    u.w[2] = pk2(hi.x, hi.y);
    u.w[3] = pk2(hi.z, hi.w);
    return u.v;
}

__global__ __launch_bounds__(256, 4) void sdt_kernel(
    const float* __restrict__ x,
    const float* __restrict__ w,
    const float* __restrict__ bias,
    const float* __restrict__ leaf,
    float* __restrict__ pred_out,
    float* __restrict__ lp_out)
{
    __shared__ __align__(16) unsigned char smem[4 * PWAVE];   // 20 KB

    const int tid  = threadIdx.x;
    const int lane = tid & 63;
    const int wave = tid >> 6;
    const int lc = lane & 15, lq = lane >> 4;   // MFMA fragment coords
    const int j = lane & 7,   rsub = lane >> 3; // walk coords

    unsigned char* Pw = smem + wave * PWAVE;

    float bias_v[8];
#pragma unroll
    for (int ct = 0; ct < 8; ++ct) {
        int node = ct * 16 + lc; if (node > 126) node = 126;
        bias_v[ct] = bias[node];
    }

    const int b2 = (j >> 2) & 1, b3 = (j >> 1) & 1, b4 = j & 1;
    const int wave_row0 = blockIdx.x * 256 + wave * 16;   // chunk ck adds ck*64

    // ---- prologue: issue chunk-0 x loads ----
    const float* xr0 = x + (size_t)(wave_row0 + lc) * 64 + lq * 8;
    v4f xa = *(const v4f*)xr0,        xb = *(const v4f*)(xr0 + 4);
    v4f xc = *(const v4f*)(xr0 + 32), xd = *(const v4f*)(xr0 + 36);

#pragma unroll
    for (int ck = 0; ck < 4; ++ck) {
        const int row0 = wave_row0 + ck * 64;

        // consume raw x regs, immediately re-issue loads for chunk ck+1
        h8 a0 = cvt8(xa, xb);
        h8 a1 = cvt8(xc, xd);
        if (ck < 3) {
            const float* xr = xr0 + (ck + 1) * 64 * 64;
            xa = *(const v4f*)xr;        xb = *(const v4f*)(xr + 4);
            xc = *(const v4f*)(xr + 32); xd = *(const v4f*)(xr + 36);
        }

        // W fragments: reloaded every chunk (L1-resident). Anti-hoist barrier
        // makes wp opaque so the 32 loads can't be hoisted out of the ck loop
        // (which would cost 64 VGPRs and the occupancy we're buying).
        const float* wp = w;
        asm volatile("" : "+s"(wp));

        // ---- MFMA: 16 rows x 128 node-cols; sigmoid; p -> LDS f16 ----
#pragma unroll
        for (int ct = 0; ct < 8; ++ct) {
            int node = ct * 16 + lc; if (node > 126) node = 126;  // col 127 pad
            const float* src = wp + node * 64 + lq * 8;
            h8 b0 = cvt8(*(const v4f*)src,        *(const v4f*)(src + 4));   // K 0..31
            h8 b1 = cvt8(*(const v4f*)(src + 32), *(const v4f*)(src + 36));  // K 32..63
            v4f acc = {};
            acc = __builtin_amdgcn_mfma_f32_16x16x32_f16(a0, b0, acc, 0, 0, 0);
            acc = __builtin_amdgcn_mfma_f32_16x16x32_f16(a1, b1, acc, 0, 0, 0);
            // C layout: col = lane&15, row = (lane>>4)*4 + i
            float s0 = fast_sigmoid(acc[0] + bias_v[ct]);
            float s1 = fast_sigmoid(acc[1] + bias_v[ct]);
            float s2 = fast_sigmoid(acc[2] + bias_v[ct]);
            float s3 = fast_sigmoid(acc[3] + bias_v[ct]);
            *(u32x2*)(Pw + (ct * 16 + lc) * PSTRIDE + lq * 8) =
                u32x2{pk2(s0, s1), pk2(s2, s3)};               // ds_write_b64
        }

        asm volatile("s_waitcnt lgkmcnt(0)" ::: "memory");  // P visible (same-wave)

        // leaf values: reloaded per chunk (512B, L1-resident) to stay under
        // the 128-VGPR cap.
        const float* lfp = leaf;
        asm volatile("" : "+s"(lfp));
        v4f leafv[4];
#pragma unroll
        for (int s = 0; s < 4; ++s) leafv[s] = *(const v4f*)(lfp + 32 * s + 4 * j);

        // ---- walk: thread = (row octet rsub, leaf quad j) ----
        auto rd = [&](int node, int row) -> float {
            return (float)*(const _Float16*)(Pw + node * PSTRIDE + row * 2);
        };

        float pa = 0.f, pb = 0.f;
#pragma unroll
        for (int i1 = 0; i1 < 2; ++i1) {
            const int row = rsub + 8 * i1;
            float p0  = rd(0, row);
            float p1a = rd(1, row), p1b = rd(2, row);
            float f01_0 = (1.f - p0) * (1.f - p1a);
            float f01_1 = (1.f - p0) * p1a;
            float f01_2 = p0 * (1.f - p1b);
            float f01_3 = p0 * p1b;
            float acc = 0.f;
            v4f* dst = (v4f*)lp_out + (size_t)(row0 + row) * 32 + j;
#pragma unroll
            for (int seg = 0; seg < 4; ++seg) {
                float f01 = seg == 0 ? f01_0 : seg == 1 ? f01_1 : seg == 2 ? f01_2 : f01_3;
                float pd2 = rd(3 + seg, row);
                float P3 = f01 * (b2 ? pd2 : 1.f - pd2);
                float pd3 = rd(7 + 2 * seg + (j >> 2), row);
                float P4 = P3 * (b3 ? pd3 : 1.f - pd3);
                float pd4 = rd(15 + 4 * seg + (j >> 1), row);
                float P5 = P4 * (b4 ? pd4 : 1.f - pd4);
                const int q = 8 * seg + j;
                float pd5 = rd(31 + q, row);
                float A = P5 * (1.f - pd5), B = P5 * pd5;
                float pl = rd(63 + 2 * q, row), pr = rd(64 + 2 * q, row);
                v4f o = { A * (1.f - pl), A * pl, B * (1.f - pr), B * pr };
                __builtin_nontemporal_store(o, dst + seg * 8);  // j=0..7 => 8 full 128B lines
                acc = fmaf(o.x, leafv[seg].x, acc);
                acc = fmaf(o.y, leafv[seg].y, acc);
                acc = fmaf(o.z, leafv[seg].z, acc);
                acc = fmaf(o.w, leafv[seg].w, acc);
            }
            if (i1 == 0) pa = acc; else pb = acc;
        }

        // pred: reduce over the 8 j-lanes of each row
#pragma unroll
        for (int s = 1; s <= 4; s <<= 1) {
            pa += __shfl_xor(pa, s, 64);
            pb += __shfl_xor(pb, s, 64);
        }
        if (j == 0) {
            pred_out[row0 + rsub]     = pa;
            pred_out[row0 + rsub + 8] = pb;
        }
    }
}

extern "C" void kernel_launch(void* const* d_in, const int* in_sizes, int n_in,
                              void* d_out, int out_size, void* d_ws, size_t ws_size,
                              hipStream_t stream) {
    const float* x    = (const float*)d_in[0];
    const float* w    = (const float*)d_in[1];
    const float* bias = (const float*)d_in[2];
    const float* leaf = (const float*)d_in[3];

    float* pred = (float*)d_out;             // BATCH floats
    float* lp   = (float*)d_out + BATCH;     // BATCH x 128 floats

    sdt_kernel<<<BATCH / 256, 256, 0, stream>>>(x, w, bias, leaf, pred, lp);
}

// Round 8
// 178.671 us; speedup vs baseline: 1.6755x; 1.6755x over previous
//
#include <hip/hip_runtime.h>

// SoftDecisionTree: BATCH=1M, DIM=64, DEPTH=7 -> 127 nodes, 128 leaves.
// Round 8 = round 6 exactly (MFMA logits, f16 P in per-wave LDS, walk with
// line-complete stores, zero barriers, pipelined x loads, bfrag hoisted,
// launch_bounds(256,3)) with ONE change:
//   nontemporal -> PLAIN stores for leaf_probs.
// Theory: NT (no-allocate) bypasses L2 write buffering; shallow write queues
// back-pressure and stall all resident waves at store issue (R7 counters:
// VALUBusy 20%, MfmaUtil 2%, HBM 25% -- nothing saturated, waves idle ~2/3).
// The harness fill kernel hits 6.5 TB/s with plain stores.

typedef float v4f __attribute__((ext_vector_type(4)));
typedef _Float16 h8 __attribute__((ext_vector_type(8)));
typedef unsigned int u32;
typedef u32 u32x2 __attribute__((ext_vector_type(2)));

constexpr int BATCH = 1 << 20;
constexpr int PSTRIDE = 40;           // bytes per node: 16 rows * 2B + 8 pad
constexpr int PWAVE = 128 * PSTRIDE;  // 5120 B per wave

__device__ __forceinline__ float fast_sigmoid(float z) {
    float e = __builtin_amdgcn_exp2f(z * -1.44269504088896340736f);
    return __builtin_amdgcn_rcpf(1.0f + e);
}

__device__ __forceinline__ u32 pk2(float a, float b) {
    return __builtin_bit_cast(u32, __builtin_amdgcn_cvt_pkrtz(a, b));
}

__device__ __forceinline__ h8 cvt8(v4f lo, v4f hi) {
    union { u32 w[4]; h8 v; } u;
    u.w[0] = pk2(lo.x, lo.y);
    u.w[1] = pk2(lo.z, lo.w);
    u.w[2] = pk2(hi.x, hi.y);
    u.w[3] = pk2(hi.z, hi.w);
    return u.v;
}

__global__ __launch_bounds__(256, 3) void sdt_kernel(
    const float* __restrict__ x,
    const float* __restrict__ w,
    const float* __restrict__ bias,
    const float* __restrict__ leaf,
    float* __restrict__ pred_out,
    float* __restrict__ lp_out)
{
    __shared__ __align__(16) unsigned char smem[4 * PWAVE];

    const int tid  = threadIdx.x;
    const int lane = tid & 63;
    const int wave = tid >> 6;
    const int lc = lane & 15, lq = lane >> 4;   // MFMA fragment coords
    const int j = lane & 7,   rsub = lane >> 3; // walk coords

    unsigned char* Pw = smem + wave * PWAVE;

    // ---- one-time: hoist B fragments (weights, f16) into VGPRs ----
    h8 bfrag[8][2];
#pragma unroll
    for (int ct = 0; ct < 8; ++ct) {
        int node = ct * 16 + lc; if (node > 126) node = 126;  // col 127 = pad
#pragma unroll
        for (int kh = 0; kh < 2; ++kh) {
            const float* src = w + node * 64 + kh * 32 + lq * 8;
            bfrag[ct][kh] = cvt8(*(const v4f*)src, *(const v4f*)(src + 4));
        }
    }
    float bias_v[8];
#pragma unroll
    for (int ct = 0; ct < 8; ++ct) {
        int node = ct * 16 + lc; if (node > 126) node = 126;
        bias_v[ct] = bias[node];
    }
    v4f leafv[4];
#pragma unroll
    for (int s = 0; s < 4; ++s) leafv[s] = *(const v4f*)(leaf + 32 * s + 4 * j);

    const int b2 = (j >> 2) & 1, b3 = (j >> 1) & 1, b4 = j & 1;
    const int wave_row0 = blockIdx.x * 256 + wave * 16;   // chunk ck adds ck*64

    // ---- prologue: issue chunk-0 x loads ----
    const float* xr0 = x + (size_t)(wave_row0 + lc) * 64 + lq * 8;
    v4f xa = *(const v4f*)xr0,        xb = *(const v4f*)(xr0 + 4);
    v4f xc = *(const v4f*)(xr0 + 32), xd = *(const v4f*)(xr0 + 36);

#pragma unroll
    for (int ck = 0; ck < 4; ++ck) {
        const int row0 = wave_row0 + ck * 64;

        // consume raw regs (vmcnt wait lands here), then immediately re-issue
        // loads for chunk ck+1 -> MFMA+walk hide their latency
        h8 a0 = cvt8(xa, xb);
        h8 a1 = cvt8(xc, xd);
        if (ck < 3) {
            const float* xr = xr0 + (ck + 1) * 64 * 64;
            xa = *(const v4f*)xr;        xb = *(const v4f*)(xr + 4);
            xc = *(const v4f*)(xr + 32); xd = *(const v4f*)(xr + 36);
        }

        // ---- MFMA: 16 rows x 128 node-cols; sigmoid; p -> LDS f16 ----
#pragma unroll
        for (int ct = 0; ct < 8; ++ct) {
            v4f acc = {};
            acc = __builtin_amdgcn_mfma_f32_16x16x32_f16(a0, bfrag[ct][0], acc, 0, 0, 0);
            acc = __builtin_amdgcn_mfma_f32_16x16x32_f16(a1, bfrag[ct][1], acc, 0, 0, 0);
            // C layout: col = lane&15, row = (lane>>4)*4 + i
            float s0 = fast_sigmoid(acc[0] + bias_v[ct]);
            float s1 = fast_sigmoid(acc[1] + bias_v[ct]);
            float s2 = fast_sigmoid(acc[2] + bias_v[ct]);
            float s3 = fast_sigmoid(acc[3] + bias_v[ct]);
            *(u32x2*)(Pw + (ct * 16 + lc) * PSTRIDE + lq * 8) =
                u32x2{pk2(s0, s1), pk2(s2, s3)};               // ds_write_b64
        }

        asm volatile("s_waitcnt lgkmcnt(0)" ::: "memory");  // P visible (same-wave)

        // ---- walk: thread = (row octet rsub, leaf quad j) ----
        auto rd = [&](int node, int row) -> float {
            return (float)*(const _Float16*)(Pw + node * PSTRIDE + row * 2);
        };

        float pa = 0.f, pb = 0.f;
#pragma unroll
        for (int i1 = 0; i1 < 2; ++i1) {
            const int row = rsub + 8 * i1;
            float p0  = rd(0, row);
            float p1a = rd(1, row), p1b = rd(2, row);
            float f01_0 = (1.f - p0) * (1.f - p1a);
            float f01_1 = (1.f - p0) * p1a;
            float f01_2 = p0 * (1.f - p1b);
            float f01_3 = p0 * p1b;
            float acc = 0.f;
            v4f* dst = (v4f*)lp_out + (size_t)(row0 + row) * 32 + j;
#pragma unroll
            for (int seg = 0; seg < 4; ++seg) {
                float f01 = seg == 0 ? f01_0 : seg == 1 ? f01_1 : seg == 2 ? f01_2 : f01_3;
                float pd2 = rd(3 + seg, row);
                float P3 = f01 * (b2 ? pd2 : 1.f - pd2);
                float pd3 = rd(7 + 2 * seg + (j >> 2), row);
                float P4 = P3 * (b3 ? pd3 : 1.f - pd3);
                float pd4 = rd(15 + 4 * seg + (j >> 1), row);
                float P5 = P4 * (b4 ? pd4 : 1.f - pd4);
                const int q = 8 * seg + j;
                float pd5 = rd(31 + q, row);
                float A = P5 * (1.f - pd5), B = P5 * pd5;
                float pl = rd(63 + 2 * q, row), pr = rd(64 + 2 * q, row);
                v4f o = { A * (1.f - pl), A * pl, B * (1.f - pr), B * pr };
                dst[seg * 8] = o;   // PLAIN store (round-8 A/B vs nontemporal)
                acc = fmaf(o.x, leafv[seg].x, acc);
                acc = fmaf(o.y, leafv[seg].y, acc);
                acc = fmaf(o.z, leafv[seg].z, acc);
                acc = fmaf(o.w, leafv[seg].w, acc);
            }
            if (i1 == 0) pa = acc; else pb = acc;
        }

        // pred: reduce over the 8 j-lanes of each row
#pragma unroll
        for (int s = 1; s <= 4; s <<= 1) {
            pa += __shfl_xor(pa, s, 64);
            pb += __shfl_xor(pb, s, 64);
        }
        if (j == 0) {
            pred_out[row0 + rsub]     = pa;
            pred_out[row0 + rsub + 8] = pb;
        }
    }
}

extern "C" void kernel_launch(void* const* d_in, const int* in_sizes, int n_in,
                              void* d_out, int out_size, void* d_ws, size_t ws_size,
                              hipStream_t stream) {
    const float* x    = (const float*)d_in[0];
    const float* w    = (const float*)d_in[1];
    const float* bias = (const float*)d_in[2];
    const float* leaf = (const float*)d_in[3];

    float* pred = (float*)d_out;             // BATCH floats
    float* lp   = (float*)d_out + BATCH;     // BATCH x 128 floats

    sdt_kernel<<<BATCH / 256, 256, 0, stream>>>(x, w, bias, leaf, pred, lp);
}

// Round 9
// 163.995 us; speedup vs baseline: 1.8254x; 1.0895x over previous
//
#include <hip/hip_runtime.h>

// SoftDecisionTree: BATCH=1M, DIM=64, DEPTH=7 -> 127 nodes, 128 leaves.
// Round 9 = round 8 (MFMA logits, f16 P per-wave LDS, line-complete plain
// stores, zero barriers in main loop, pipelined x loads) with an occupancy
// push done RIGHT this time (R7's failed push added a serial L2 chain):
//   - W no longer hoisted into 64 VGPRs: staged ONCE into block-shared LDS
//     (f16, 16KB, XOR-swizzled: node*128B stride is a 16-way bank conflict
//     otherwise). B-frags = 16x ds_read_b128 per chunk, overlappable.
//   - __launch_bounds__(256,4): VGPR cap 128, 4 blocks/CU (LDS 36.9KB also
//     caps at 4) = 16 waves/CU (+33% vs round 8).
//   - walk select trim: (b ? p : 1-p) = fmaf(s, p, o), s/o per-lane consts.

typedef float v4f __attribute__((ext_vector_type(4)));
typedef _Float16 h8 __attribute__((ext_vector_type(8)));
typedef unsigned int u32;
typedef u32 u32x2 __attribute__((ext_vector_type(2)));

constexpr int BATCH = 1 << 20;
constexpr int PSTRIDE = 40;             // bytes per node: 16 rows * 2B + 8 pad
constexpr int PWAVE = 128 * PSTRIDE;    // 5120 B per wave
constexpr int W_BYTES = 128 * 128;      // 16 KB: 128 nodes x 64 f16
constexpr int P_OFF = W_BYTES;

__device__ __forceinline__ float fast_sigmoid(float z) {
    float e = __builtin_amdgcn_exp2f(z * -1.44269504088896340736f);
    return __builtin_amdgcn_rcpf(1.0f + e);
}

__device__ __forceinline__ u32 pk2(float a, float b) {
    return __builtin_bit_cast(u32, __builtin_amdgcn_cvt_pkrtz(a, b));
}

__device__ __forceinline__ h8 cvt8(v4f lo, v4f hi) {
    union { u32 w[4]; h8 v; } u;
    u.w[0] = pk2(lo.x, lo.y);
    u.w[1] = pk2(lo.z, lo.w);
    u.w[2] = pk2(hi.x, hi.y);
    u.w[3] = pk2(hi.z, hi.w);
    return u.v;
}

__global__ __launch_bounds__(256, 4) void sdt_kernel(
    const float* __restrict__ x,
    const float* __restrict__ w,
    const float* __restrict__ bias,
    const float* __restrict__ leaf,
    float* __restrict__ pred_out,
    float* __restrict__ lp_out)
{
    __shared__ __align__(16) unsigned char smem[W_BYTES + 4 * PWAVE];  // 36.9 KB

    const int tid  = threadIdx.x;
    const int lane = tid & 63;
    const int wave = tid >> 6;
    const int lc = lane & 15, lq = lane >> 4;   // MFMA fragment coords
    const int j = lane & 7,   rsub = lane >> 3; // walk coords

    unsigned char* WL = smem;                    // block-shared weights (f16, swizzled)
    unsigned char* Pw = smem + P_OFF + wave * PWAVE;

    // ---- one-time: stage W -> LDS f16 with XOR swizzle; node 127 zeroed ----
    for (int idx = tid; idx < 128 * 8; idx += 256) {
        int node = idx >> 3, c = idx & 7;        // c = 16B chunk within the 128B row
        v4f f0 = {}, f1 = {};
        if (node < 127) {
            const float* sp = w + node * 64 + c * 8;
            f0 = *(const v4f*)sp; f1 = *(const v4f*)(sp + 4);
        }
        int off = node * 128 + ((c * 16) ^ ((node & 7) << 4));
        *(h8*)(WL + off) = cvt8(f0, f1);
    }

    float bias_v[8];
#pragma unroll
    for (int ct = 0; ct < 8; ++ct) {
        int node = ct * 16 + lc; if (node > 126) node = 126;
        bias_v[ct] = bias[node];
    }
    v4f leafv[4];
#pragma unroll
    for (int s = 0; s < 4; ++s) leafv[s] = *(const v4f*)(leaf + 32 * s + 4 * j);

    // per-lane select constants: (b ? p : 1-p) == fmaf(s, p, o)
    const int b2 = (j >> 2) & 1, b3 = (j >> 1) & 1, b4 = j & 1;
    const float s2 = b2 ? 1.f : -1.f, o2 = b2 ? 0.f : 1.f;
    const float s3 = b3 ? 1.f : -1.f, o3 = b3 ? 0.f : 1.f;
    const float s4 = b4 ? 1.f : -1.f, o4 = b4 ? 0.f : 1.f;

    const int wave_row0 = blockIdx.x * 256 + wave * 16;   // chunk ck adds ck*64
    const int wsw = (lc & 7) << 4;                        // W read swizzle (node&7 == lc&7)

    // ---- prologue: issue chunk-0 x loads ----
    const float* xr0 = x + (size_t)(wave_row0 + lc) * 64 + lq * 8;
    v4f xa = *(const v4f*)xr0,        xb = *(const v4f*)(xr0 + 4);
    v4f xc = *(const v4f*)(xr0 + 32), xd = *(const v4f*)(xr0 + 36);

    __syncthreads();   // W staged (once; main loop has no barriers)

#pragma unroll
    for (int ck = 0; ck < 4; ++ck) {
        const int row0 = wave_row0 + ck * 64;

        // consume raw x regs, immediately re-issue loads for chunk ck+1
        h8 a0 = cvt8(xa, xb);
        h8 a1 = cvt8(xc, xd);
        if (ck < 3) {
            const float* xr = xr0 + (ck + 1) * 64 * 64;
            xa = *(const v4f*)xr;        xb = *(const v4f*)(xr + 4);
            xc = *(const v4f*)(xr + 32); xd = *(const v4f*)(xr + 36);
        }

        // ---- MFMA: 16 rows x 128 node-cols; sigmoid; p -> LDS f16 ----
#pragma unroll
        for (int ct = 0; ct < 8; ++ct) {
            const unsigned char* wrow = WL + (ct * 16 + lc) * 128;
            h8 b0 = *(const h8*)(wrow + ((lq * 16)      ^ wsw));   // K 0..31
            h8 b1 = *(const h8*)(wrow + ((64 + lq * 16) ^ wsw));   // K 32..63
            v4f acc = {};
            acc = __builtin_amdgcn_mfma_f32_16x16x32_f16(a0, b0, acc, 0, 0, 0);
            acc = __builtin_amdgcn_mfma_f32_16x16x32_f16(a1, b1, acc, 0, 0, 0);
            // C layout: col = lane&15, row = (lane>>4)*4 + i
            float s0 = fast_sigmoid(acc[0] + bias_v[ct]);
            float s1 = fast_sigmoid(acc[1] + bias_v[ct]);
            float sS2 = fast_sigmoid(acc[2] + bias_v[ct]);
            float sS3 = fast_sigmoid(acc[3] + bias_v[ct]);
            *(u32x2*)(Pw + (ct * 16 + lc) * PSTRIDE + lq * 8) =
                u32x2{pk2(s0, s1), pk2(sS2, sS3)};               // ds_write_b64
        }

        asm volatile("s_waitcnt lgkmcnt(0)" ::: "memory");  // P visible (same-wave)

        // ---- walk: thread = (row octet rsub, leaf quad j) ----
        auto rd = [&](int node, int row) -> float {
            return (float)*(const _Float16*)(Pw + node * PSTRIDE + row * 2);
        };

        float pa = 0.f, pb = 0.f;
#pragma unroll
        for (int i1 = 0; i1 < 2; ++i1) {
            const int row = rsub + 8 * i1;
            float p0  = rd(0, row);
            float p1a = rd(1, row), p1b = rd(2, row);
            float f01_0 = (1.f - p0) * (1.f - p1a);
            float f01_1 = (1.f - p0) * p1a;
            float f01_2 = p0 * (1.f - p1b);
            float f01_3 = p0 * p1b;
            float acc = 0.f;
            v4f* dst = (v4f*)lp_out + (size_t)(row0 + row) * 32 + j;
#pragma unroll
            for (int seg = 0; seg < 4; ++seg) {
                float f01 = seg == 0 ? f01_0 : seg == 1 ? f01_1 : seg == 2 ? f01_2 : f01_3;
                float P3 = f01 * fmaf(s2, rd(3 + seg, row), o2);
                float P4 = P3  * fmaf(s3, rd(7 + 2 * seg + (j >> 2), row), o3);
                float P5 = P4  * fmaf(s4, rd(15 + 4 * seg + (j >> 1), row), o4);
                const int q = 8 * seg + j;
                float pd5 = rd(31 + q, row);
                float A = P5 * (1.f - pd5), B = P5 * pd5;
                float pl = rd(63 + 2 * q, row), pr = rd(64 + 2 * q, row);
                v4f o = { A * (1.f - pl), A * pl, B * (1.f - pr), B * pr };
                dst[seg * 8] = o;   // lanes j=0..7 tile 8 complete 128B lines
                acc = fmaf(o.x, leafv[seg].x, acc);
                acc = fmaf(o.y, leafv[seg].y, acc);
                acc = fmaf(o.z, leafv[seg].z, acc);
                acc = fmaf(o.w, leafv[seg].w, acc);
            }
            if (i1 == 0) pa = acc; else pb = acc;
        }

        // pred: reduce over the 8 j-lanes of each row
#pragma unroll
        for (int s = 1; s <= 4; s <<= 1) {
            pa += __shfl_xor(pa, s, 64);
            pb += __shfl_xor(pb, s, 64);
        }
        if (j == 0) {
            pred_out[row0 + rsub]     = pa;
            pred_out[row0 + rsub + 8] = pb;
        }
    }
}

extern "C" void kernel_launch(void* const* d_in, const int* in_sizes, int n_in,
                              void* d_out, int out_size, void* d_ws, size_t ws_size,
                              hipStream_t stream) {
    const float* x    = (const float*)d_in[0];
    const float* w    = (const float*)d_in[1];
    const float* bias = (const float*)d_in[2];
    const float* leaf = (const float*)d_in[3];

    float* pred = (float*)d_out;             // BATCH floats
    float* lp   = (float*)d_out + BATCH;     // BATCH x 128 floats

    sdt_kernel<<<BATCH / 256, 256, 0, stream>>>(x, w, bias, leaf, pred, lp);
}